// Round 2
// baseline (331.358 us; speedup 1.0000x reference)
//
#include <hip/hip_runtime.h>
#include <hip/hip_bf16.h>
#include <stdint.h>

// Problem constants (mask is deterministic: arange(L) >= int(0.9*L) = 1843)
#define B_  2
#define L_  2048
#define D_  1024
#define H_  16
#define DH_ 64
#define NVALID 1843   // keys >= 1843 are padding

typedef __attribute__((ext_vector_type(8))) short bf16x8;   // 8 bf16 = 4 VGPRs
typedef __attribute__((ext_vector_type(4))) float f32x4;
typedef __hip_bfloat16 bf16;

__device__ inline float bf2f(bf16 v) { return __bfloat162float(v); }
__device__ inline bf16  f2bf(float v) { return __float2bfloat16(v); }

// ---------------------------------------------------------------------------
// Transpose + convert: out[c][r] = bf16(in[r][c]); in fp32 (rows x cols)
// ---------------------------------------------------------------------------
__global__ __launch_bounds__(256) void transpose_f32_bf16(
    const float* __restrict__ in, bf16* __restrict__ out, int rows, int cols)
{
    __shared__ float tile[32][33];   // +1 pad breaks bank-conflict stride
    const int bx = blockIdx.x * 32;             // col base (input)
    const int by = blockIdx.y * 32;             // row base (input)
    const int tx = threadIdx.x & 31, ty = threadIdx.x >> 5;   // 32 x 8
#pragma unroll
    for (int i = 0; i < 32; i += 8)
        tile[ty + i][tx] = in[(size_t)(by + ty + i) * cols + (bx + tx)];
    __syncthreads();
#pragma unroll
    for (int i = 0; i < 32; i += 8)
        out[(size_t)(bx + ty + i) * rows + (by + tx)] = f2bf(tile[tx][ty + i]);
}

// ---------------------------------------------------------------------------
// Elementwise fp32 -> bf16 convert (n multiple of 4)
// ---------------------------------------------------------------------------
__global__ __launch_bounds__(256) void convert_f32_bf16(
    const float* __restrict__ in, bf16* __restrict__ out, int n)
{
    const int i = (blockIdx.x * 256 + threadIdx.x) * 4;
    if (i < n) {
        const float4 v = *reinterpret_cast<const float4*>(&in[i]);
        bf16 tmp[4];
        tmp[0] = f2bf(v.x); tmp[1] = f2bf(v.y);
        tmp[2] = f2bf(v.z); tmp[3] = f2bf(v.w);
        *reinterpret_cast<ushort4*>(&out[i]) = *reinterpret_cast<const ushort4*>(tmp);
    }
}

// ---------------------------------------------------------------------------
// GEMM (B^T form): C(M,N) = X(M,K) @ Wt(N,K)^T + bias   (X, Wt bf16; bias fp32)
// 128x128 tile, BK=32, 256 threads = 4 waves, each wave a 64x64 quadrant
// MODE 0: fp32 store to out (row-major M x N)
// MODE 1: QKV scatter -> Q (scaled by 1/8), K, V^T   (bf16)
// ---------------------------------------------------------------------------
template <int MODE>
__global__ __launch_bounds__(256) void gemm_bt(
    const bf16* __restrict__ X, const bf16* __restrict__ Wt,
    const float* __restrict__ bias, float* __restrict__ out,
    bf16* __restrict__ Qb, bf16* __restrict__ Kb, bf16* __restrict__ Vt,
    int M, int N, int K)
{
    __shared__ bf16 Xs[128 * 32];
    __shared__ bf16 Ws[128 * 32];

    const int t    = threadIdx.x;
    const int m0   = blockIdx.y * 128;
    const int n0   = blockIdx.x * 128;
    const int w    = t >> 6, lane = t & 63;
    const int quad = lane >> 4, lr = lane & 15;
    const int wm   = (w >> 1) * 64, wn = (w & 1) * 64;

    const f32x4 fzero = {0.f, 0.f, 0.f, 0.f};
    f32x4 acc[4][4];
#pragma unroll
    for (int i = 0; i < 4; i++)
#pragma unroll
        for (int j = 0; j < 4; j++) acc[i][j] = fzero;

    const int row = t >> 2;          // 0..63
    const int cg  = (t & 3) * 8;     // 0,8,16,24 (elements)

    for (int k0 = 0; k0 < K; k0 += 32) {
        __syncthreads();             // previous iter's readers done
        *reinterpret_cast<uint4*>(&Xs[(row      ) * 32 + cg]) =
            *reinterpret_cast<const uint4*>(&X[(size_t)(m0 + row     ) * K + k0 + cg]);
        *reinterpret_cast<uint4*>(&Xs[(row + 64 ) * 32 + cg]) =
            *reinterpret_cast<const uint4*>(&X[(size_t)(m0 + row + 64) * K + k0 + cg]);
        *reinterpret_cast<uint4*>(&Ws[(row      ) * 32 + cg]) =
            *reinterpret_cast<const uint4*>(&Wt[(size_t)(n0 + row     ) * K + k0 + cg]);
        *reinterpret_cast<uint4*>(&Ws[(row + 64 ) * 32 + cg]) =
            *reinterpret_cast<const uint4*>(&Wt[(size_t)(n0 + row + 64) * K + k0 + cg]);
        __syncthreads();

        bf16x8 a[4], b[4];
#pragma unroll
        for (int i = 0; i < 4; i++) {
            a[i] = *reinterpret_cast<const bf16x8*>(&Xs[(wm + i * 16 + lr) * 32 + quad * 8]);
            b[i] = *reinterpret_cast<const bf16x8*>(&Ws[(wn + i * 16 + lr) * 32 + quad * 8]);
        }
#pragma unroll
        for (int i = 0; i < 4; i++)
#pragma unroll
            for (int j = 0; j < 4; j++)
                acc[i][j] = __builtin_amdgcn_mfma_f32_16x16x32_bf16(a[i], b[j], acc[i][j], 0, 0, 0);
    }

    // epilogue: C row = m0+wm+i*16+quad*4+r ; col = n0+wn+j*16+lr
#pragma unroll
    for (int j = 0; j < 4; j++) {
        const int n  = n0 + wn + j * 16 + lr;
        const float bn = bias[n];
#pragma unroll
        for (int i = 0; i < 4; i++) {
#pragma unroll
            for (int r = 0; r < 4; r++) {
                const int m = m0 + wm + i * 16 + quad * 4 + r;
                const float v = acc[i][j][r] + bn;
                if (MODE == 0) {
                    out[(size_t)m * N + n] = v;
                } else {
                    // n -> (s, h, dh); m -> (b, l)
                    const int s  = n >> 10;           // 0=q 1=k 2=v (uniform per block)
                    const int h  = (n >> 6) & (H_ - 1);
                    const int dh = n & (DH_ - 1);
                    const int bb = m >> 11;
                    const int l  = m & (L_ - 1);
                    const int bh = bb * H_ + h;
                    if (s == 0)      Qb[((size_t)bh * L_  + l ) * DH_ + dh] = f2bf(v * 0.125f); // fold DH^-0.5
                    else if (s == 1) Kb[((size_t)bh * L_  + l ) * DH_ + dh] = f2bf(v);
                    else             Vt[((size_t)bh * DH_ + dh) * L_  + l ] = f2bf(v);
                }
            }
        }
    }
}

// ---------------------------------------------------------------------------
// Flash attention: one block per (b, h, q-tile of 128). 4 waves x 32 q-rows.
// Q pre-scaled. Online softmax; P round-trips LDS (C-layout -> A-layout).
// ---------------------------------------------------------------------------
__global__ __launch_bounds__(256) void attn_kernel(
    const bf16* __restrict__ Qb, const bf16* __restrict__ Kb,
    const bf16* __restrict__ Vt, bf16* __restrict__ attn)
{
    __shared__ bf16 Ks[128 * 64];    // [key][dh]
    __shared__ bf16 Vs[64 * 128];    // [dh][key]
    __shared__ bf16 Ps[128 * 128];   // [qrow][key]

    const int t    = threadIdx.x;
    const int w    = t >> 6, lane = t & 63;
    const int quad = lane >> 4, lr = lane & 15;
    const int bh   = blockIdx.x >> 4;      // b*H + h
    const int qt   = blockIdx.x & 15;
    const int wq   = qt * 128 + w * 32;    // wave's first q row

    // Q fragments (A-layout): rows wq + mi*16 + lr, k = ks*32 + quad*8
    bf16x8 aQ[2][2];
#pragma unroll
    for (int mi = 0; mi < 2; mi++)
#pragma unroll
        for (int ks = 0; ks < 2; ks++)
            aQ[mi][ks] = *reinterpret_cast<const bf16x8*>(
                &Qb[((size_t)bh * L_ + (wq + mi * 16 + lr)) * DH_ + ks * 32 + quad * 8]);

    const f32x4 fzero = {0.f, 0.f, 0.f, 0.f};
    f32x4 O[2][4];
    float mrow[2][4], lrow[2][4];
#pragma unroll
    for (int i = 0; i < 2; i++)
#pragma unroll
        for (int j = 0; j < 4; j++) O[i][j] = fzero;
#pragma unroll
    for (int i = 0; i < 2; i++)
#pragma unroll
        for (int r = 0; r < 4; r++) { mrow[i][r] = -30000.f; lrow[i][r] = 0.f; }

    const float LOG2E = 1.44269504f;

    for (int kt = 0; kt < 15; kt++) {       // tile 15 fully masked -> skipped
        const int kv0 = kt * 128;
        __syncthreads();
        {   // stage K tile: 128 rows x 64 = contiguous 8192 elems
            const bf16* src = &Kb[((size_t)bh * L_ + kv0) * DH_];
#pragma unroll
            for (int p = 0; p < 4; p++) {
                const int off = (p * 256 + t) * 8;
                *reinterpret_cast<uint4*>(&Ks[off]) =
                    *reinterpret_cast<const uint4*>(&src[off]);
            }
            // stage V^T tile: 64 rows (dh) x 128 keys
#pragma unroll
            for (int p = 0; p < 4; p++) {
                const int r = p * 16 + (t >> 4);
                const int c = (t & 15) * 8;
                *reinterpret_cast<uint4*>(&Vs[r * 128 + c]) =
                    *reinterpret_cast<const uint4*>(&Vt[((size_t)bh * DH_ + r) * L_ + kv0 + c]);
            }
        }
        __syncthreads();

        // S = Q @ K^T : 32 x 128 per wave
        f32x4 S[2][8];
#pragma unroll
        for (int mi = 0; mi < 2; mi++)
#pragma unroll
            for (int ni = 0; ni < 8; ni++) S[mi][ni] = fzero;
#pragma unroll
        for (int ks = 0; ks < 2; ks++) {
            bf16x8 bK[8];
#pragma unroll
            for (int ni = 0; ni < 8; ni++)
                bK[ni] = *reinterpret_cast<const bf16x8*>(
                    &Ks[(ni * 16 + lr) * 64 + ks * 32 + quad * 8]);
#pragma unroll
            for (int mi = 0; mi < 2; mi++)
#pragma unroll
                for (int ni = 0; ni < 8; ni++)
                    S[mi][ni] = __builtin_amdgcn_mfma_f32_16x16x32_bf16(
                        aQ[mi][ks], bK[ni], S[mi][ni], 0, 0, 0);
        }

        // key-padding mask (only the boundary tile); bounded magnitude
        if (kv0 + 128 > NVALID) {
#pragma unroll
            for (int ni = 0; ni < 8; ni++) {
                const int key = kv0 + ni * 16 + lr;
                if (key >= NVALID) {
#pragma unroll
                    for (int mi = 0; mi < 2; mi++)
#pragma unroll
                        for (int r = 0; r < 4; r++) S[mi][ni][r] = -30000.f;
                }
            }
        }

        // online softmax (rows = quad*4 + r per 16-tile; cross-lane over 16 cols)
#pragma unroll
        for (int mi = 0; mi < 2; mi++) {
            float mx[4], al[4];
#pragma unroll
            for (int r = 0; r < 4; r++) {
                float v = S[mi][0][r];
#pragma unroll
                for (int ni = 1; ni < 8; ni++) v = fmaxf(v, S[mi][ni][r]);
#pragma unroll
                for (int off = 1; off < 16; off <<= 1) v = fmaxf(v, __shfl_xor(v, off));
                const float mn = fmaxf(mrow[mi][r], v);
                al[r] = exp2f((mrow[mi][r] - mn) * LOG2E);
                mrow[mi][r] = mn;
                mx[r] = mn;
            }
            float rs[4] = {0.f, 0.f, 0.f, 0.f};
#pragma unroll
            for (int ni = 0; ni < 8; ni++) {
#pragma unroll
                for (int r = 0; r < 4; r++) {
                    const float p = exp2f((S[mi][ni][r] - mx[r]) * LOG2E);
                    rs[r] += p;
                    Ps[(w * 32 + mi * 16 + quad * 4 + r) * 128 + ni * 16 + lr] = f2bf(p);
                }
            }
#pragma unroll
            for (int r = 0; r < 4; r++) {
                float v = rs[r];
#pragma unroll
                for (int off = 1; off < 16; off <<= 1) v += __shfl_xor(v, off);
                lrow[mi][r] = lrow[mi][r] * al[r] + v;
            }
#pragma unroll
            for (int di = 0; di < 4; di++)
#pragma unroll
                for (int r = 0; r < 4; r++) O[mi][di][r] *= al[r];
        }

        // O += P @ V : A from Ps (own rows only -> no cross-wave sync needed)
#pragma unroll
        for (int ks = 0; ks < 4; ks++) {
            bf16x8 aP[2], bV[4];
#pragma unroll
            for (int mi = 0; mi < 2; mi++)
                aP[mi] = *reinterpret_cast<const bf16x8*>(
                    &Ps[(w * 32 + mi * 16 + lr) * 128 + ks * 32 + quad * 8]);
#pragma unroll
            for (int di = 0; di < 4; di++)
                bV[di] = *reinterpret_cast<const bf16x8*>(
                    &Vs[(di * 16 + lr) * 128 + ks * 32 + quad * 8]);
#pragma unroll
            for (int mi = 0; mi < 2; mi++)
#pragma unroll
                for (int di = 0; di < 4; di++)
                    O[mi][di] = __builtin_amdgcn_mfma_f32_16x16x32_bf16(
                        aP[mi], bV[di], O[mi][di], 0, 0, 0);
        }
    }

    // epilogue: attn[(b,l,h*64+dh)] = O / l
    const int b = bh >> 4, h = bh & (H_ - 1);
#pragma unroll
    for (int mi = 0; mi < 2; mi++)
#pragma unroll
        for (int di = 0; di < 4; di++)
#pragma unroll
            for (int r = 0; r < 4; r++) {
                const int qrow = wq + mi * 16 + quad * 4 + r;
                const int dh   = di * 16 + lr;
                attn[((size_t)b * L_ + qrow) * D_ + h * DH_ + dh] =
                    f2bf(O[mi][di][r] / lrow[mi][r]);
            }
}

// ---------------------------------------------------------------------------
extern "C" void kernel_launch(void* const* d_in, const int* in_sizes, int n_in,
                              void* d_out, int out_size, void* d_ws, size_t ws_size,
                              hipStream_t stream)
{
    const float* x     = (const float*)d_in[0];   // (B*L, D) fp32
    const float* w_qkv = (const float*)d_in[1];   // (D, 3D)  fp32
    const float* b_qkv = (const float*)d_in[2];   // (3D,)    fp32
    const float* w_out = (const float*)d_in[3];   // (D, D)   fp32
    const float* b_out = (const float*)d_in[4];   // (D,)     fp32
    float* out = (float*)d_out;                   // (B*L, D) fp32

    // workspace carve-up (48 MB total)
    char* ws = (char*)d_ws;
    bf16* xb    = (bf16*)ws; ws += (size_t)B_ * L_ * D_ * 2;       // (B*L, D)
    bf16* wqkvT = (bf16*)ws; ws += (size_t)3 * D_ * D_ * 2;        // (3072,1024)
    bf16* woutT = (bf16*)ws; ws += (size_t)D_ * D_ * 2;            // (1024,1024)
    bf16* Qb    = (bf16*)ws; ws += (size_t)B_ * H_ * L_ * DH_ * 2; // (B,H,L,DH), pre-scaled
    bf16* Kb    = (bf16*)ws; ws += (size_t)B_ * H_ * L_ * DH_ * 2; // (B,H,L,DH)
    bf16* Vt    = (bf16*)ws; ws += (size_t)B_ * H_ * L_ * DH_ * 2; // (B,H,DH,L)
    bf16* attn  = (bf16*)ws;                                       // (B,L,D)

    convert_f32_bf16<<<(B_ * L_ * D_) / (256 * 4), 256, 0, stream>>>(x, xb, B_ * L_ * D_);
    transpose_f32_bf16<<<dim3(3 * D_ / 32, D_ / 32), 256, 0, stream>>>(w_qkv, wqkvT, D_, 3 * D_);
    transpose_f32_bf16<<<dim3(D_ / 32, D_ / 32), 256, 0, stream>>>(w_out, woutT, D_, D_);

    gemm_bt<1><<<dim3(3 * D_ / 128, (B_ * L_) / 128), 256, 0, stream>>>(
        xb, wqkvT, b_qkv, nullptr, Qb, Kb, Vt, B_ * L_, 3 * D_, D_);

    attn_kernel<<<B_ * H_ * (L_ / 128), 256, 0, stream>>>(Qb, Kb, Vt, attn);

    gemm_bt<0><<<dim3(D_ / 128, (B_ * L_) / 128), 256, 0, stream>>>(
        attn, woutT, b_out, out, nullptr, nullptr, nullptr, B_ * L_, D_, D_);
}

// Round 3
// 260.443 us; speedup vs baseline: 1.2723x; 1.2723x over previous
//
#include <hip/hip_runtime.h>
#include <hip/hip_bf16.h>
#include <stdint.h>

// Problem constants (mask is deterministic: arange(L) >= int(0.9*L) = 1843)
#define B_  2
#define L_  2048
#define D_  1024
#define H_  16
#define DH_ 64
#define NVALID 1843   // keys >= 1843 are padding

typedef __attribute__((ext_vector_type(8))) short bf16x8;   // 8 bf16 = 4 VGPRs
typedef __attribute__((ext_vector_type(4))) float f32x4;
typedef __hip_bfloat16 bf16;

__device__ inline float bf2f(bf16 v) { return __bfloat162float(v); }
__device__ inline bf16  f2bf(float v) { return __float2bfloat16(v); }

// ---------------------------------------------------------------------------
// Transpose + convert: out[c][r] = bf16(in[r][c]); in fp32 (rows x cols)
// ---------------------------------------------------------------------------
__global__ __launch_bounds__(256) void transpose_f32_bf16(
    const float* __restrict__ in, bf16* __restrict__ out, int rows, int cols)
{
    __shared__ float tile[32][33];   // +1 pad breaks bank-conflict stride
    const int bx = blockIdx.x * 32;             // col base (input)
    const int by = blockIdx.y * 32;             // row base (input)
    const int tx = threadIdx.x & 31, ty = threadIdx.x >> 5;   // 32 x 8
#pragma unroll
    for (int i = 0; i < 32; i += 8)
        tile[ty + i][tx] = in[(size_t)(by + ty + i) * cols + (bx + tx)];
    __syncthreads();
#pragma unroll
    for (int i = 0; i < 32; i += 8)
        out[(size_t)(bx + ty + i) * rows + (by + tx)] = f2bf(tile[tx][ty + i]);
}

// ---------------------------------------------------------------------------
// Elementwise fp32 -> bf16 convert (n multiple of 4)
// ---------------------------------------------------------------------------
__global__ __launch_bounds__(256) void convert_f32_bf16(
    const float* __restrict__ in, bf16* __restrict__ out, int n)
{
    const int i = (blockIdx.x * 256 + threadIdx.x) * 4;
    if (i < n) {
        const float4 v = *reinterpret_cast<const float4*>(&in[i]);
        bf16 tmp[4];
        tmp[0] = f2bf(v.x); tmp[1] = f2bf(v.y);
        tmp[2] = f2bf(v.z); tmp[3] = f2bf(v.w);
        *reinterpret_cast<ushort4*>(&out[i]) = *reinterpret_cast<const ushort4*>(tmp);
    }
}

// ---------------------------------------------------------------------------
// GEMM (B^T form): C(M,N) = X(M,K) @ Wt(N,K)^T + bias   (X, Wt bf16; bias fp32)
// 128x128 tile, BK=32, 256 threads = 4 waves, each wave a 64x64 quadrant
// MODE 0: fp32 store to out (row-major M x N)
// MODE 1: QKV scatter -> Q (scaled by SCALE*LOG2E), K, V^T   (bf16)
// ---------------------------------------------------------------------------
template <int MODE>
__global__ __launch_bounds__(256) void gemm_bt(
    const bf16* __restrict__ X, const bf16* __restrict__ Wt,
    const float* __restrict__ bias, float* __restrict__ out,
    bf16* __restrict__ Qb, bf16* __restrict__ Kb, bf16* __restrict__ Vt,
    int M, int N, int K)
{
    __shared__ bf16 Xs[128 * 32];
    __shared__ bf16 Ws[128 * 32];

    const int t    = threadIdx.x;
    const int m0   = blockIdx.y * 128;
    const int n0   = blockIdx.x * 128;
    const int w    = t >> 6, lane = t & 63;
    const int quad = lane >> 4, lr = lane & 15;
    const int wm   = (w >> 1) * 64, wn = (w & 1) * 64;

    const f32x4 fzero = {0.f, 0.f, 0.f, 0.f};
    f32x4 acc[4][4];
#pragma unroll
    for (int i = 0; i < 4; i++)
#pragma unroll
        for (int j = 0; j < 4; j++) acc[i][j] = fzero;

    const int row = t >> 2;          // 0..63
    const int cg  = (t & 3) * 8;     // 0,8,16,24 (elements)

    for (int k0 = 0; k0 < K; k0 += 32) {
        __syncthreads();             // previous iter's readers done
        *reinterpret_cast<uint4*>(&Xs[(row      ) * 32 + cg]) =
            *reinterpret_cast<const uint4*>(&X[(size_t)(m0 + row     ) * K + k0 + cg]);
        *reinterpret_cast<uint4*>(&Xs[(row + 64 ) * 32 + cg]) =
            *reinterpret_cast<const uint4*>(&X[(size_t)(m0 + row + 64) * K + k0 + cg]);
        *reinterpret_cast<uint4*>(&Ws[(row      ) * 32 + cg]) =
            *reinterpret_cast<const uint4*>(&Wt[(size_t)(n0 + row     ) * K + k0 + cg]);
        *reinterpret_cast<uint4*>(&Ws[(row + 64 ) * 32 + cg]) =
            *reinterpret_cast<const uint4*>(&Wt[(size_t)(n0 + row + 64) * K + k0 + cg]);
        __syncthreads();

        bf16x8 a[4], b[4];
#pragma unroll
        for (int i = 0; i < 4; i++) {
            a[i] = *reinterpret_cast<const bf16x8*>(&Xs[(wm + i * 16 + lr) * 32 + quad * 8]);
            b[i] = *reinterpret_cast<const bf16x8*>(&Ws[(wn + i * 16 + lr) * 32 + quad * 8]);
        }
#pragma unroll
        for (int i = 0; i < 4; i++)
#pragma unroll
            for (int j = 0; j < 4; j++)
                acc[i][j] = __builtin_amdgcn_mfma_f32_16x16x32_bf16(a[i], b[j], acc[i][j], 0, 0, 0);
    }

    // epilogue: C row = m0+wm+i*16+quad*4+r ; col = n0+wn+j*16+lr
#pragma unroll
    for (int j = 0; j < 4; j++) {
        const int n  = n0 + wn + j * 16 + lr;
        const float bn = bias[n];
#pragma unroll
        for (int i = 0; i < 4; i++) {
#pragma unroll
            for (int r = 0; r < 4; r++) {
                const int m = m0 + wm + i * 16 + quad * 4 + r;
                const float v = acc[i][j][r] + bn;
                if (MODE == 0) {
                    out[(size_t)m * N + n] = v;
                } else {
                    // n -> (s, h, dh); m -> (b, l)
                    const int s  = n >> 10;           // 0=q 1=k 2=v (uniform per block)
                    const int h  = (n >> 6) & (H_ - 1);
                    const int dh = n & (DH_ - 1);
                    const int bb = m >> 11;
                    const int l  = m & (L_ - 1);
                    const int bh = bb * H_ + h;
                    // fold DH^-0.5 * log2(e) into Q so attn softmax uses exp2 directly
                    if (s == 0)      Qb[((size_t)bh * L_  + l ) * DH_ + dh] = f2bf(v * 0.1803368801f);
                    else if (s == 1) Kb[((size_t)bh * L_  + l ) * DH_ + dh] = f2bf(v);
                    else             Vt[((size_t)bh * DH_ + dh) * L_  + l ] = f2bf(v);
                }
            }
        }
    }
}

// ---------------------------------------------------------------------------
// Flash attention, S^T formulation: one block per (b, h, q-tile of 128).
// 4 waves x 32 q-rows. QK^T computed as S^T = K @ Q^T so that C-layout gives
// col(lane)=qrow, row(quad*4+r)=key: softmax is in-lane over keys, and P can
// be stored to LDS with vector b64 writes (4 consecutive keys per lane).
// LDS strides padded (+8) for even bank spread. P stored in two 64-col
// halves to stay under 64 KB. Q pre-scaled by SCALE*LOG2E (exp2 softmax).
// ---------------------------------------------------------------------------
#define KST 72    // Ks row stride (elems)
#define VST 136   // Vs row stride
#define PST 72    // Ps row stride (64-key half-tile)

__global__ __launch_bounds__(256) void attn_kernel(
    const bf16* __restrict__ Qb, const bf16* __restrict__ Kb,
    const bf16* __restrict__ Vt, bf16* __restrict__ attn)
{
    __shared__ bf16 Ks[128 * KST];   // 18432 B  [key][dh]
    __shared__ bf16 Vs[64 * VST];    // 17408 B  [dh][key]
    __shared__ bf16 Ps[128 * PST];   // 18432 B  [qrow][key-half]   total 54272 B

    const int t    = threadIdx.x;
    const int w    = t >> 6, lane = t & 63;
    const int quad = lane >> 4, lr = lane & 15;
    const int bh   = blockIdx.x >> 4;      // b*H + h
    const int qt   = blockIdx.x & 15;
    const int wq   = qt * 128 + w * 32;    // wave's first q row

    // Q B-fragments: B[k=dh][n=qrow]; lane: qrow = wq+mi*16+lr, dh = ks*32+quad*8..+7
    bf16x8 bQ[2][2];
#pragma unroll
    for (int mi = 0; mi < 2; mi++)
#pragma unroll
        for (int ks = 0; ks < 2; ks++)
            bQ[mi][ks] = *reinterpret_cast<const bf16x8*>(
                &Qb[((size_t)bh * L_ + (wq + mi * 16 + lr)) * DH_ + ks * 32 + quad * 8]);

    const f32x4 fzero = {0.f, 0.f, 0.f, 0.f};
    f32x4 O[2][4];                    // O[qrow][dh]: row=quad*4+r -> qrow, col=lr -> dh
    float m_i[2], l_i[2];             // per-lane state for qrow = wq+mi*16+lr
#pragma unroll
    for (int i = 0; i < 2; i++) {
#pragma unroll
        for (int j = 0; j < 4; j++) O[i][j] = fzero;
        m_i[i] = -30000.f; l_i[i] = 0.f;
    }

    for (int kt = 0; kt < 15; kt++) {       // tile 15 fully masked -> skipped
        const int kv0 = kt * 128;
        __syncthreads();
        {   // stage K tile: 128 rows x 64, padded stride
            const bf16* srcK = &Kb[((size_t)bh * L_ + kv0) * DH_];
#pragma unroll
            for (int p = 0; p < 4; p++) {
                const int e = p * 256 + t;
                const int row = e >> 3, col = (e & 7) * 8;
                *reinterpret_cast<uint4*>(&Ks[row * KST + col]) =
                    *reinterpret_cast<const uint4*>(&srcK[row * 64 + col]);
            }
            // stage V^T tile: 64 rows (dh) x 128 keys, padded stride
#pragma unroll
            for (int p = 0; p < 4; p++) {
                const int r = p * 16 + (t >> 4);
                const int c = (t & 15) * 8;
                *reinterpret_cast<uint4*>(&Vs[r * VST + c]) =
                    *reinterpret_cast<const uint4*>(&Vt[((size_t)bh * DH_ + r) * L_ + kv0 + c]);
            }
        }
        __syncthreads();

        // S^T = K @ Q^T : St[mi][ni] lane holds key = kv0+ni*16+quad*4+r, qrow = wq+mi*16+lr
        f32x4 St[2][8];
#pragma unroll
        for (int mi = 0; mi < 2; mi++)
#pragma unroll
            for (int ni = 0; ni < 8; ni++) St[mi][ni] = fzero;
#pragma unroll
        for (int ks = 0; ks < 2; ks++) {
            bf16x8 aK[8];
#pragma unroll
            for (int ni = 0; ni < 8; ni++)
                aK[ni] = *reinterpret_cast<const bf16x8*>(
                    &Ks[(ni * 16 + lr) * KST + ks * 32 + quad * 8]);
#pragma unroll
            for (int ni = 0; ni < 8; ni++)
#pragma unroll
                for (int mi = 0; mi < 2; mi++)
                    St[mi][ni] = __builtin_amdgcn_mfma_f32_16x16x32_bf16(
                        aK[ni], bQ[mi][ks], St[mi][ni], 0, 0, 0);
        }

        // key-padding mask (keys are in-register now)
        if (kv0 + 128 > NVALID) {
#pragma unroll
            for (int ni = 0; ni < 8; ni++)
#pragma unroll
                for (int r = 0; r < 4; r++) {
                    const int key = kv0 + ni * 16 + quad * 4 + r;
                    if (key >= NVALID) { St[0][ni][r] = -30000.f; St[1][ni][r] = -30000.f; }
                }
        }

        // online softmax: in-lane over 32 (ni,r) + 2 cross-quad shuffles
#pragma unroll
        for (int mi = 0; mi < 2; mi++) {
            float mx = St[mi][0][0];
#pragma unroll
            for (int ni = 0; ni < 8; ni++)
#pragma unroll
                for (int r = 0; r < 4; r++) mx = fmaxf(mx, St[mi][ni][r]);
            mx = fmaxf(mx, __shfl_xor(mx, 16));
            mx = fmaxf(mx, __shfl_xor(mx, 32));
            const float mn    = fmaxf(m_i[mi], mx);
            const float alpha = exp2f(m_i[mi] - mn);
            m_i[mi] = mn;
            float s = 0.f;
#pragma unroll
            for (int ni = 0; ni < 8; ni++)
#pragma unroll
                for (int r = 0; r < 4; r++) {
                    const float pv = exp2f(St[mi][ni][r] - mn);
                    St[mi][ni][r] = pv;          // St now holds P^T
                    s += pv;
                }
            s += __shfl_xor(s, 16);
            s += __shfl_xor(s, 32);
            l_i[mi] = l_i[mi] * alpha + s;
            // redistribute alpha to O rows (qrow = quad*4+r lives at lane lr'=quad*4+r)
            float a_r[4];
#pragma unroll
            for (int r = 0; r < 4; r++)
                a_r[r] = __shfl(alpha, (lane & 48) | (quad * 4 + r));
#pragma unroll
            for (int di = 0; di < 4; di++)
#pragma unroll
                for (int r = 0; r < 4; r++) O[mi][di][r] *= a_r[r];
        }

        // O += P @ V in two 64-key halves (Ps holds one half at a time)
#pragma unroll
        for (int half = 0; half < 2; half++) {
            // store P half: lane owns 4 consecutive keys per (mi,nn) -> b64 store
#pragma unroll
            for (int mi = 0; mi < 2; mi++)
#pragma unroll
                for (int nn = 0; nn < 4; nn++) {
                    const int ni = half * 4 + nn;
                    bf16 tmp[4];
#pragma unroll
                    for (int r = 0; r < 4; r++) tmp[r] = f2bf(St[mi][ni][r]);
                    *reinterpret_cast<ushort4*>(
                        &Ps[(w * 32 + mi * 16 + lr) * PST + nn * 16 + quad * 4]) =
                        *reinterpret_cast<const ushort4*>(tmp);
                }
            // PV for this half's two 32-key MFMA steps (wave-private rows, no barrier)
#pragma unroll
            for (int kk = 0; kk < 2; kk++) {
                const int ks = half * 2 + kk;
                bf16x8 bV[4];
#pragma unroll
                for (int di = 0; di < 4; di++)
                    bV[di] = *reinterpret_cast<const bf16x8*>(
                        &Vs[(di * 16 + lr) * VST + ks * 32 + quad * 8]);
#pragma unroll
                for (int mi = 0; mi < 2; mi++) {
                    const bf16x8 aP = *reinterpret_cast<const bf16x8*>(
                        &Ps[(w * 32 + mi * 16 + lr) * PST + kk * 32 + quad * 8]);
#pragma unroll
                    for (int di = 0; di < 4; di++)
                        O[mi][di] = __builtin_amdgcn_mfma_f32_16x16x32_bf16(
                            aP, bV[di], O[mi][di], 0, 0, 0);
                }
            }
        }
    }

    // epilogue: attn[(b, qrow, h*64+dh)] = O / l   (l lives at lane lr'=quad*4+r)
    const int b = bh >> 4, h = bh & (H_ - 1);
#pragma unroll
    for (int mi = 0; mi < 2; mi++) {
        float linv[4];
#pragma unroll
        for (int r = 0; r < 4; r++)
            linv[r] = 1.f / __shfl(l_i[mi], (lane & 48) | (quad * 4 + r));
#pragma unroll
        for (int di = 0; di < 4; di++)
#pragma unroll
            for (int r = 0; r < 4; r++) {
                const int qrow = wq + mi * 16 + quad * 4 + r;
                const int dh   = di * 16 + lr;
                attn[((size_t)b * L_ + qrow) * D_ + h * DH_ + dh] =
                    f2bf(O[mi][di][r] * linv[r]);
            }
    }
}

// ---------------------------------------------------------------------------
extern "C" void kernel_launch(void* const* d_in, const int* in_sizes, int n_in,
                              void* d_out, int out_size, void* d_ws, size_t ws_size,
                              hipStream_t stream)
{
    const float* x     = (const float*)d_in[0];   // (B*L, D) fp32
    const float* w_qkv = (const float*)d_in[1];   // (D, 3D)  fp32
    const float* b_qkv = (const float*)d_in[2];   // (3D,)    fp32
    const float* w_out = (const float*)d_in[3];   // (D, D)   fp32
    const float* b_out = (const float*)d_in[4];   // (D,)     fp32
    float* out = (float*)d_out;                   // (B*L, D) fp32

    // workspace carve-up (48 MB total)
    char* ws = (char*)d_ws;
    bf16* xb    = (bf16*)ws; ws += (size_t)B_ * L_ * D_ * 2;       // (B*L, D)
    bf16* wqkvT = (bf16*)ws; ws += (size_t)3 * D_ * D_ * 2;        // (3072,1024)
    bf16* woutT = (bf16*)ws; ws += (size_t)D_ * D_ * 2;            // (1024,1024)
    bf16* Qb    = (bf16*)ws; ws += (size_t)B_ * H_ * L_ * DH_ * 2; // (B,H,L,DH), pre-scaled
    bf16* Kb    = (bf16*)ws; ws += (size_t)B_ * H_ * L_ * DH_ * 2; // (B,H,L,DH)
    bf16* Vt    = (bf16*)ws; ws += (size_t)B_ * H_ * L_ * DH_ * 2; // (B,H,DH,L)
    bf16* attn  = (bf16*)ws;                                       // (B,L,D)

    convert_f32_bf16<<<(B_ * L_ * D_) / (256 * 4), 256, 0, stream>>>(x, xb, B_ * L_ * D_);
    transpose_f32_bf16<<<dim3(3 * D_ / 32, D_ / 32), 256, 0, stream>>>(w_qkv, wqkvT, D_, 3 * D_);
    transpose_f32_bf16<<<dim3(D_ / 32, D_ / 32), 256, 0, stream>>>(w_out, woutT, D_, D_);

    gemm_bt<1><<<dim3(3 * D_ / 128, (B_ * L_) / 128), 256, 0, stream>>>(
        xb, wqkvT, b_qkv, nullptr, Qb, Kb, Vt, B_ * L_, 3 * D_, D_);

    attn_kernel<<<B_ * H_ * (L_ / 128), 256, 0, stream>>>(Qb, Kb, Vt, attn);

    gemm_bt<0><<<dim3(D_ / 128, (B_ * L_) / 128), 256, 0, stream>>>(
        attn, woutT, b_out, out, nullptr, nullptr, nullptr, B_ * L_, D_, D_);
}